// Round 6
// baseline (261.825 us; speedup 1.0000x reference)
//
#include <hip/hip_runtime.h>
#include <hip/hip_bf16.h>

// EAConv: EM-routing neighbor aggregation + temporal blend.
// T=3, b=1, n=50000, d=64, m=16, K=4, dd=16.
// R6: TWO nodes per wave (independent chains interleave -> in-wave ILP hides
// gather latency + DPP-tree latency; 2x outstanding loads). Keeps R5's packed
// math, logit-fold (u unnormalized, rsqrt folded into logit), R3's clean
// 4-branch store pattern (extended to lanes m=0..7 for the two nodes).
// Lane = (k,m): m=lane&15 neighbor, k=lane>>4 factor.

typedef float v2f __attribute__((ext_vector_type(2)));

constexpr int T  = 3;
constexpr int N  = 50000;
constexpr int D  = 64;
constexpr int M  = 16;
constexpr int DD = 16;
constexpr float EPS2 = 1e-24f;  // (1e-12)^2

template <int CTRL>
__device__ __forceinline__ float dpp_add(float v) {
    // v + (v rotated within the 16-lane row); fuses to v_add_f32_dpp
    int rot = __builtin_amdgcn_update_dpp(
        0, __float_as_int(v), CTRL, 0xF, 0xF, false);
    return v + __int_as_float(rot);
}
// sum over the 16 lanes of a row; result broadcast to every lane of the row
__device__ __forceinline__ float rowsum16(float v) {
    v = dpp_add<0x128>(v);  // row_ror:8
    v = dpp_add<0x124>(v);  // row_ror:4
    v = dpp_add<0x122>(v);  // row_ror:2
    v = dpp_add<0x121>(v);  // row_ror:1
    return v;
}

__global__ __launch_bounds__(256) void eaconv_agg(
    const float* __restrict__ x_all,   // [T,N,D]
    const int*   __restrict__ nbr_all, // [T,N,M]
    float*       __restrict__ out)     // [T,N,D] <- U_t (pre-blend)
{
    const int wave = (blockIdx.x * blockDim.x + threadIdx.x) >> 6;
    const int lane = threadIdx.x & 63;
    const int half = N / 2;            // node pairs per t
    if (wave >= T * half) return;
    const int t  = wave / half;
    const int i0 = (wave - t * half) * 2;   // this wave handles i0, i0+1
    const int m = lane & 15;
    const int k = lane >> 4;

    const float* x = x_all + (size_t)t * N * D;

    // ---- issue ALL loads up front (2 idx + 16 row loads in flight) ----
    int jj[2];
    bool valid[2];
#pragma unroll
    for (int nn = 0; nn < 2; ++nn) {
        int j = nbr_all[((size_t)t * N + (i0 + nn)) * M + m];
        valid[nn] = (unsigned)j < (unsigned)N;
        jj[nn] = valid[nn] ? j : 0;
    }

    v2f xk[2][8], z[2][8], u[2][8];
#pragma unroll
    for (int nn = 0; nn < 2; ++nn) {
        const float4* xr = (const float4*)(x + (size_t)(i0 + nn) * D + k * DD);
        const float4* zr = (const float4*)(x + (size_t)jj[nn] * D + k * DD);
        float4 a0 = xr[0], a1 = xr[1], a2 = xr[2], a3 = xr[3];
        float4 b0 = zr[0], b1 = zr[1], b2 = zr[2], b3 = zr[3];
        xk[nn][0] = {a0.x,a0.y}; xk[nn][1] = {a0.z,a0.w};
        xk[nn][2] = {a1.x,a1.y}; xk[nn][3] = {a1.z,a1.w};
        xk[nn][4] = {a2.x,a2.y}; xk[nn][5] = {a2.z,a2.w};
        xk[nn][6] = {a3.x,a3.y}; xk[nn][7] = {a3.z,a3.w};
        z[nn][0]  = {b0.x,b0.y}; z[nn][1]  = {b0.z,b0.w};
        z[nn][2]  = {b1.x,b1.y}; z[nn][3]  = {b1.z,b1.w};
        z[nn][4]  = {b2.x,b2.y}; z[nn][5]  = {b2.z,b2.w};
        z[nn][6]  = {b3.x,b3.y}; z[nn][7]  = {b3.z,b3.w};
    }

    // ---- normalize both nodes' rows (two independent chains) ----
#pragma unroll
    for (int nn = 0; nn < 2; ++nn) {
        v2f sx = xk[nn][0] * xk[nn][0], sz = z[nn][0] * z[nn][0];
#pragma unroll
        for (int q = 1; q < 8; ++q) {
            sx = __builtin_elementwise_fma(xk[nn][q], xk[nn][q], sx);
            sz = __builtin_elementwise_fma(z[nn][q],  z[nn][q],  sz);
        }
        const float rx = __builtin_amdgcn_rsqf(fmaxf(sx.x + sx.y, EPS2));
        float rz = __builtin_amdgcn_rsqf(fmaxf(sz.x + sz.y, EPS2));
        if (!valid[nn]) rz = 0.f;
#pragma unroll
        for (int q = 0; q < 8; ++q) { xk[nn][q] *= rx; z[nn][q] *= rz; }
    }

    // ---- iter 0: u = sum_m z + 4*xk (direction; scale folds into logit) ----
    float inv[2];
#pragma unroll
    for (int nn = 0; nn < 2; ++nn) {
#pragma unroll
        for (int q = 0; q < 8; ++q) {
            v2f s;
            s.x = rowsum16(z[nn][q].x);
            s.y = rowsum16(z[nn][q].y);
            u[nn][q] = __builtin_elementwise_fma(xk[nn][q], (v2f)(4.0f), s);
        }
        v2f ns = u[nn][0] * u[nn][0];
#pragma unroll
        for (int q = 1; q < 8; ++q)
            ns = __builtin_elementwise_fma(u[nn][q], u[nn][q], ns);
        inv[nn] = __builtin_amdgcn_rsqf(fmaxf(ns.x + ns.y, EPS2));
    }

    // ---- iters 1..2 ----
#pragma unroll
    for (int it = 1; it < 3; ++it) {
#pragma unroll
        for (int nn = 0; nn < 2; ++nn) {
            v2f da = z[nn][0] * u[nn][0];
#pragma unroll
            for (int q = 1; q < 8; ++q)
                da = __builtin_elementwise_fma(z[nn][q], u[nn][q], da);
            const float logit = (da.x + da.y) * inv[nn];  // in [-1,1]
            const float e = __expf(logit);
            float es = e + __shfl_xor(e, 16, 64);
            es += __shfl_xor(es, 32, 64);
            const float w = e * __builtin_amdgcn_rcpf(es);
#pragma unroll
            for (int q = 0; q < 8; ++q) {
                v2f wz = z[nn][q] * w;
                v2f s;
                s.x = rowsum16(wz.x);
                s.y = rowsum16(wz.y);
                u[nn][q] = xk[nn][q] + s;
            }
            if (it < 2) {  // no normalize after the last iteration
                v2f na = u[nn][0] * u[nn][0];
#pragma unroll
                for (int q = 1; q < 8; ++q)
                    na = __builtin_elementwise_fma(u[nn][q], u[nn][q], na);
                inv[nn] = __builtin_amdgcn_rsqf(fmaxf(na.x + na.y, EPS2));
            }
        }
    }

    // ---- store: lanes m=0..3 write node i0's four float4 slices,
    //      lanes m=4..7 write node i0+1's (u replicated across each row) ----
    float* o0 = out + ((size_t)t * N + i0) * D + k * DD;
    float* o1 = o0 + D;
    if (m == 0) ((float4*)o0)[0] = make_float4(u[0][0].x,u[0][0].y,u[0][1].x,u[0][1].y);
    if (m == 1) ((float4*)o0)[1] = make_float4(u[0][2].x,u[0][2].y,u[0][3].x,u[0][3].y);
    if (m == 2) ((float4*)o0)[2] = make_float4(u[0][4].x,u[0][4].y,u[0][5].x,u[0][5].y);
    if (m == 3) ((float4*)o0)[3] = make_float4(u[0][6].x,u[0][6].y,u[0][7].x,u[0][7].y);
    if (m == 4) ((float4*)o1)[0] = make_float4(u[1][0].x,u[1][0].y,u[1][1].x,u[1][1].y);
    if (m == 5) ((float4*)o1)[1] = make_float4(u[1][2].x,u[1][2].y,u[1][3].x,u[1][3].y);
    if (m == 6) ((float4*)o1)[2] = make_float4(u[1][4].x,u[1][4].y,u[1][5].x,u[1][5].y);
    if (m == 7) ((float4*)o1)[3] = make_float4(u[1][6].x,u[1][6].y,u[1][7].x,u[1][7].y);
}

// Temporal blend, closed form (sigmoid(0)=0.5, sigmoid(1)=0.7310585786):
//   e0 = u0;  e1 = 0.25*u0 + 0.5*u1;  e2 = (0.5*u0 + s1*e1)*0.25 + 0.5*u2
__global__ __launch_bounds__(256) void eaconv_combine(float* __restrict__ out) {
    const int nd4 = N * D / 4;
    int idx = blockIdx.x * blockDim.x + threadIdx.x;
    if (idx >= nd4) return;
    float4* o = (float4*)out;
    float4 u0 = o[idx];
    float4 u1 = o[nd4 + idx];
    float4 u2 = o[2 * nd4 + idx];
    const float s1 = 0.7310585786300049f;
    float4 e1, e2;
    e1.x = 0.25f * u0.x + 0.5f * u1.x;
    e1.y = 0.25f * u0.y + 0.5f * u1.y;
    e1.z = 0.25f * u0.z + 0.5f * u1.z;
    e1.w = 0.25f * u0.w + 0.5f * u1.w;
    e2.x = (0.5f * u0.x + s1 * e1.x) * 0.25f + 0.5f * u2.x;
    e2.y = (0.5f * u0.y + s1 * e1.y) * 0.25f + 0.5f * u2.y;
    e2.z = (0.5f * u0.z + s1 * e1.z) * 0.25f + 0.5f * u2.z;
    e2.w = (0.5f * u0.w + s1 * e1.w) * 0.25f + 0.5f * u2.w;
    o[nd4 + idx] = e1;
    o[2 * nd4 + idx] = e2;
}

extern "C" void kernel_launch(void* const* d_in, const int* in_sizes, int n_in,
                              void* d_out, int out_size, void* d_ws, size_t ws_size,
                              hipStream_t stream) {
    const float* x_all = (const float*)d_in[0];
    const int*   nbrs  = (const int*)d_in[1];
    float*       out   = (float*)d_out;

    // one wave per node PAIR: 75000 waves, 4 waves/block -> 18750 blocks
    const int total_threads = T * (N / 2) * 64;
    eaconv_agg<<<(total_threads + 255) / 256, 256, 0, stream>>>(x_all, nbrs, out);
    eaconv_combine<<<(N * D / 4 + 255) / 256, 256, 0, stream>>>(out);
}

// Round 7
// 240.496 us; speedup vs baseline: 1.0887x; 1.0887x over previous
//
#include <hip/hip_runtime.h>
#include <hip/hip_bf16.h>

// EAConv: EM-routing neighbor aggregation + temporal blend.
// T=3, b=1, n=50000, d=64, m=16, K=4, dd=16.
// R7 = R3 structure (one node/wave, scalar f32, clean 4-branch store) with
// minimum instruction count:
//  - rowsum16 via __builtin_amdgcn_mov_dpp (undef old -> GCNDPPCombine can
//    fuse mov_dpp+add into v_add_f32_dpp: 4 instr/rowsum, not 8)
//  - u kept UNNORMALIZED; rsqrt(||u||^2) folded into the scalar logit
//  - z kept RAW; 1/||z|| folded into the per-lane scalar weight (w*rz), so
//    invalid neighbors are handled by rz=0 alone (no 16-reg zeroing)
// Lane = (k,m): m=lane&15 neighbor, k=lane>>4 factor; lane holds neighbor
// m's full 16-dim factor-k row.

constexpr int T  = 3;
constexpr int N  = 50000;
constexpr int D  = 64;
constexpr int M  = 16;
constexpr int DD = 16;
constexpr float EPS2 = 1e-24f;  // (1e-12)^2

template <int CTRL>
__device__ __forceinline__ float dpp_add(float v) {
    // mov_dpp has an implicit UNDEF old operand -> eligible for fusion into
    // v_add_f32_dpp. row_ror within a 16-lane row: every lane valid.
    int rot = __builtin_amdgcn_mov_dpp(__float_as_int(v), CTRL, 0xF, 0xF, false);
    return v + __int_as_float(rot);
}
// sum over the 16 lanes of a row; result broadcast to every lane of the row
__device__ __forceinline__ float rowsum16(float v) {
    v = dpp_add<0x128>(v);  // row_ror:8
    v = dpp_add<0x124>(v);  // row_ror:4
    v = dpp_add<0x122>(v);  // row_ror:2
    v = dpp_add<0x121>(v);  // row_ror:1
    return v;
}

__global__ __launch_bounds__(256) void eaconv_agg(
    const float* __restrict__ x_all,   // [T,N,D]
    const int*   __restrict__ nbr_all, // [T,N,M]
    float*       __restrict__ out)     // [T,N,D] <- U_t (pre-blend)
{
    const int wave = (blockIdx.x * blockDim.x + threadIdx.x) >> 6;
    const int lane = threadIdx.x & 63;
    if (wave >= T * N) return;
    const int t = wave / N;
    const int i = wave - t * N;
    const int m = lane & 15;
    const int k = lane >> 4;

    const float* x = x_all + (size_t)t * N * D;

    int j = nbr_all[((size_t)t * N + i) * M + m];
    const bool valid = (unsigned)j < (unsigned)N;
    j = valid ? j : 0;

    // own factor row (broadcast addr across row) + neighbor row (scattered)
    const float4* xr = (const float4*)(x + (size_t)i * D + k * DD);
    const float4* zr = (const float4*)(x + (size_t)j * D + k * DD);
    float4 a0 = xr[0], a1 = xr[1], a2 = xr[2], a3 = xr[3];
    float4 b0 = zr[0], b1 = zr[1], b2 = zr[2], b3 = zr[3];
    float xk[DD] = {a0.x,a0.y,a0.z,a0.w, a1.x,a1.y,a1.z,a1.w,
                    a2.x,a2.y,a2.z,a2.w, a3.x,a3.y,a3.z,a3.w};
    float z[DD]  = {b0.x,b0.y,b0.z,b0.w, b1.x,b1.y,b1.z,b1.w,
                    b2.x,b2.y,b2.z,b2.w, b3.x,b3.y,b3.z,b3.w};

    // xk: normalize in place.  z: stays RAW; rz folds into the weights.
    float sx = xk[0]*xk[0], sz = z[0]*z[0];
#pragma unroll
    for (int p = 1; p < DD; ++p) { sx = fmaf(xk[p], xk[p], sx);
                                   sz = fmaf(z[p],  z[p],  sz); }
    const float rx = __builtin_amdgcn_rsqf(fmaxf(sx, EPS2));
    float rz = __builtin_amdgcn_rsqf(fmaxf(sz, EPS2));
    if (!valid) rz = 0.f;
#pragma unroll
    for (int p = 0; p < DD; ++p) xk[p] *= rx;

    // ---- iter 0: u = sum_m rz_m*z_m + 4*xk (direction; scale via logit) ----
    float u[DD];
#pragma unroll
    for (int p = 0; p < DD; ++p)
        u[p] = fmaf(xk[p], 4.0f, rowsum16(z[p] * rz));
    float ns = u[0]*u[0];
#pragma unroll
    for (int p = 1; p < DD; ++p) ns = fmaf(u[p], u[p], ns);
    float inv = __builtin_amdgcn_rsqf(fmaxf(ns, EPS2));

    // ---- iters 1..2 ----
#pragma unroll
    for (int it = 1; it < 3; ++it) {
        float dot = z[0]*u[0];
#pragma unroll
        for (int p = 1; p < DD; ++p) dot = fmaf(z[p], u[p], dot);
        const float logit = dot * (rz * inv);  // = zhat . uhat, in [-1,1]
        const float e = __expf(logit);         // no max-sub needed (bounded)
        float es = e + __shfl_xor(e, 16, 64);  // softmax denom over 4 factors
        es += __shfl_xor(es, 32, 64);
        const float wf = e * __builtin_amdgcn_rcpf(es) * rz;  // weight*rz
#pragma unroll
        for (int p = 0; p < DD; ++p)
            u[p] = xk[p] + rowsum16(z[p] * wf);
        if (it < 2) {  // no normalize after the last iteration
            float na = u[0]*u[0];
#pragma unroll
            for (int p = 1; p < DD; ++p) na = fmaf(u[p], u[p], na);
            inv = __builtin_amdgcn_rsqf(fmaxf(na, EPS2));
        }
    }

    // store (clean 37.5 MB pattern): lanes m=0..3 write one float4 each
    float* o = out + ((size_t)t * N + i) * D + k * DD;
    if (m == 0) ((float4*)o)[0] = make_float4(u[0],  u[1],  u[2],  u[3]);
    if (m == 1) ((float4*)o)[1] = make_float4(u[4],  u[5],  u[6],  u[7]);
    if (m == 2) ((float4*)o)[2] = make_float4(u[8],  u[9],  u[10], u[11]);
    if (m == 3) ((float4*)o)[3] = make_float4(u[12], u[13], u[14], u[15]);
}

// Temporal blend, closed form (sigmoid(0)=0.5, sigmoid(1)=0.7310585786):
//   e0 = u0;  e1 = 0.25*u0 + 0.5*u1;  e2 = (0.5*u0 + s1*e1)*0.25 + 0.5*u2
__global__ __launch_bounds__(256) void eaconv_combine(float* __restrict__ out) {
    const int nd4 = N * D / 4;
    int idx = blockIdx.x * blockDim.x + threadIdx.x;
    if (idx >= nd4) return;
    float4* o = (float4*)out;
    float4 u0 = o[idx];
    float4 u1 = o[nd4 + idx];
    float4 u2 = o[2 * nd4 + idx];
    const float s1 = 0.7310585786300049f;
    float4 e1, e2;
    e1.x = 0.25f * u0.x + 0.5f * u1.x;
    e1.y = 0.25f * u0.y + 0.5f * u1.y;
    e1.z = 0.25f * u0.z + 0.5f * u1.z;
    e1.w = 0.25f * u0.w + 0.5f * u1.w;
    e2.x = (0.5f * u0.x + s1 * e1.x) * 0.25f + 0.5f * u2.x;
    e2.y = (0.5f * u0.y + s1 * e1.y) * 0.25f + 0.5f * u2.y;
    e2.z = (0.5f * u0.z + s1 * e1.z) * 0.25f + 0.5f * u2.z;
    e2.w = (0.5f * u0.w + s1 * e1.w) * 0.25f + 0.5f * u2.w;
    o[nd4 + idx] = e1;
    o[2 * nd4 + idx] = e2;
}

extern "C" void kernel_launch(void* const* d_in, const int* in_sizes, int n_in,
                              void* d_out, int out_size, void* d_ws, size_t ws_size,
                              hipStream_t stream) {
    const float* x_all = (const float*)d_in[0];
    const int*   nbrs  = (const int*)d_in[1];
    float*       out   = (float*)d_out;

    const int total_threads = T * N * 64;  // one wave per (t,node)
    eaconv_agg<<<(total_threads + 255) / 256, 256, 0, stream>>>(x_all, nbrs, out);
    eaconv_combine<<<(N * D / 4 + 255) / 256, 256, 0, stream>>>(out);
}